// Round 4
// baseline (27862.494 us; speedup 1.0000x reference)
//
#include <hip/hip_runtime.h>
#include <hip/hip_fp16.h>

#define BB 64
#define TT 2048
#define NCB 8        // col-blocks: each owns 32 h-dims (128 gate cols)
#define NBG 16       // batch-groups of 4 batches
#define BPG 4
#define NTHR 768
#define RS 264       // rows stride (f16), 16B-aligned rows

typedef _Float16 h2t   __attribute__((ext_vector_type(2)));
typedef _Float16 f16x4 __attribute__((ext_vector_type(4)));
typedef _Float16 f16x8 __attribute__((ext_vector_type(8)));
union V8 { f16x8 v; h2t p[4]; };
union HU { _Float16 h; unsigned short u; };
union DU { unsigned int u; h2t h; };

__device__ __forceinline__ float sigm(float v){ return __builtin_amdgcn_rcpf(1.f+__expf(-v)); }
__device__ __forceinline__ float tanh_f(float v){ float e=__expf(2.f*v); return 1.f-2.f*__builtin_amdgcn_rcpf(e+1.f); }

__global__ void init_ws(int* __restrict__ flg){
    int i = blockIdx.x*256 + threadIdx.x;
    if (i < 2*NBG*NCB*16) flg[i] = 0;
}

__global__ __launch_bounds__(NTHR, 1) void lstm_ws(
    const float* __restrict__ x,
    const float* __restrict__ W_xh, const float* __restrict__ b_xh,
    const float* __restrict__ W_hh, const float* __restrict__ b_hh,
    float* __restrict__ out,
    unsigned int* __restrict__ hbuf,   // [2 par][16 bg][8 cb][128 dw]
    int* __restrict__ flg)             // [2 par][16 bg][8 cb][16] (64B-spaced)
{
    __shared__ _Float16 Wlds[2*32768];      // [ty][kk 32][col 128][8], stride-1 packed
    __shared__ _Float16 rows[12*RS];        // 0-3: x, 4-7: h0, 8-11: h1 (k-index = dim)
    __shared__ float    g_lds[12*2*128];    // [row][ks][col]

    const int tid = threadIdx.x;
    const int bid = blockIdx.x;
    const int cb  = bid & 7;
    const int bg  = bid >> 3;
    const int b0  = bg * BPG;

    // ---- one-time: stage weight slices f32 -> f16, packed [k/8][col][8] ----
    for (int i = tid; i < 2*256*128; i += NTHR) {
        int ty = i >> 15;
        int rem = i & 32767;
        int k  = rem >> 7;
        int cl = rem & 127;          // local col = g*32 + d
        int g = cl >> 5, d = cl & 31;
        const float* W = ty ? W_hh : W_xh;
        Wlds[ty*32768 + (k>>3)*1024 + cl*8 + (k&7)] =
            (_Float16)W[(size_t)k*1024 + g*256 + cb*32 + d];
    }
    for (int i = tid; i < 12*RS; i += NTHR) rows[i] = (_Float16)0;

    // update-thread setup (tid < 256)
    float bx[4] = {0,0,0,0}, bh[4] = {0,0,0,0};
    float c_st = 0.f;
    int u_bl = 0, u_l = 0, u_d = 0;
    if (tid < 256) {
        u_bl = tid >> 6; u_l = (tid >> 5) & 1; u_d = tid & 31;
        for (int g = 0; g < 4; ++g) {
            bx[g] = b_xh[g*256 + cb*32 + u_d];
            bh[g] = b_hh[g*256 + cb*32 + u_d];
        }
    }
    __syncthreads();

    // stage x(0)
    if (tid >= 512) {
        int t2 = tid - 512, bl = t2 >> 6, kq = t2 & 63;
        float4 v = *(const float4*)&x[((size_t)(b0+bl)*TT + 0)*256 + kq*4];
        f16x4 h; h[0]=(_Float16)v.x; h[1]=(_Float16)v.y; h[2]=(_Float16)v.z; h[3]=(_Float16)v.w;
        *(f16x4*)&rows[bl*RS + kq*4] = h;
    }
    __syncthreads();

    // dot mapping: tid = rg*256 + ks*128 + col
    const int col = tid & 127;
    const int ks  = (tid >> 7) & 1;
    const int rg  = tid >> 8;            // 0: x rows, 1: h0 rows, 2: h1 rows
    const int rb  = rg * 4;
    const _Float16* wbase = Wlds + (rg ? 1 : 0)*32768 + ks*16384 + col*8;
    const _Float16* rbase = rows + rb*RS + ks*128;

    const size_t FIN = (size_t)BB*TT*256;

    for (int p = 0; p <= TT; ++p) {
        const int par = p & 1;

        // prefetch x(p+1) into regs
        float4 xv = {0.f,0.f,0.f,0.f};
        int xbl = 0, xkq = 0;
        if (tid >= 512 && p + 1 < TT) {
            int t2 = tid - 512; xbl = t2 >> 6; xkq = t2 & 63;
            xv = *(const float4*)&x[((size_t)(b0+xbl)*TT + (p+1))*256 + xkq*4];
        }

        // dots: 4 rows x 1 col over k-half (128)
        float a0=0.f, a1=0.f, a2=0.f, a3=0.f;
#pragma unroll 4
        for (int kk = 0; kk < 16; ++kk) {
            V8 wv, r0, r1, r2, r3;
            wv.v = *(const f16x8*)&wbase[kk*1024];
            r0.v = *(const f16x8*)&rbase[kk*8];
            r1.v = *(const f16x8*)&rbase[RS + kk*8];
            r2.v = *(const f16x8*)&rbase[2*RS + kk*8];
            r3.v = *(const f16x8*)&rbase[3*RS + kk*8];
#pragma unroll
            for (int q = 0; q < 4; ++q) {
                a0 = __builtin_amdgcn_fdot2(r0.p[q], wv.p[q], a0, false);
                a1 = __builtin_amdgcn_fdot2(r1.p[q], wv.p[q], a1, false);
                a2 = __builtin_amdgcn_fdot2(r2.p[q], wv.p[q], a2, false);
                a3 = __builtin_amdgcn_fdot2(r3.p[q], wv.p[q], a3, false);
            }
        }
        g_lds[((rb+0)*2 + ks)*128 + col] = a0;
        g_lds[((rb+1)*2 + ks)*128 + col] = a1;
        g_lds[((rb+2)*2 + ks)*128 + col] = a2;
        g_lds[((rb+3)*2 + ks)*128 + col] = a3;
        __syncthreads();   // S1: dots done, g_lds ready, rows free

        // update: layer0 step p, layer1 step p-1
        float hn = 0.f;
        if (tid < 256) {
            const bool active = u_l ? (p >= 1) : (p < TT);
            if (active) {
                float gi, gf, gg, go;
                {
                    const int r1 = (u_l ? 8 : 0) + u_bl;   // x rows for l0, h1 rows for l1
                    const int r0 = 4 + u_bl;               // h0 rows (shared)
                    const float* gA = &g_lds[r0*256];
                    const float* gB = &g_lds[r1*256];
                    int c0 = u_d, c1 = 32+u_d, c2 = 64+u_d, c3 = 96+u_d;
                    gi = gA[c0] + gA[128+c0] + gB[c0] + gB[128+c0];
                    gf = gA[c1] + gA[128+c1] + gB[c1] + gB[128+c1];
                    gg = gA[c2] + gA[128+c2] + gB[c2] + gB[128+c2];
                    go = gA[c3] + gA[128+c3] + gB[c3] + gB[128+c3];
                }
                if (u_l == 0) { gi += bx[0]+bh[0]; gf += bx[1]+bh[1]; gg += bx[2]+bh[2]; go += bx[3]+bh[3]; }
                else          { gi += 2.f*bh[0];   gf += 2.f*bh[1];   gg += 2.f*bh[2];   go += 2.f*bh[3];   }
                float cn = c_st*sigm(gf) + sigm(gi)*tanh_f(gg);
                hn = sigm(go)*tanh_f(cn);
                c_st = cn;
                if (u_l) out[((size_t)(b0+u_bl)*TT + (p-1))*256 + cb*32 + u_d] = hn;
                if (u_l == 0 && p == TT-1) {
                    out[FIN +          (b0+u_bl)*256 + cb*32 + u_d] = hn;
                    out[FIN + 32768 +  (b0+u_bl)*256 + cb*32 + u_d] = cn;
                }
                if (u_l == 1 && p == TT) {
                    out[FIN + 16384 +         (b0+u_bl)*256 + cb*32 + u_d] = hn;
                    out[FIN + 32768 + 16384 + (b0+u_bl)*256 + cb*32 + u_d] = cn;
                }
            }
            // own h slice -> rows (local)
            rows[((u_l ? 8 : 4) + u_bl)*RS + cb*32 + u_d] = (_Float16)hn;
            // publish packed pair -> hbuf
            float hn_hi = __shfl_xor(hn, 1);
            if (p < TT && !(u_d & 1)) {
                HU lo, hi; lo.h = (_Float16)hn; hi.h = (_Float16)hn_hi;
                unsigned int uu = (unsigned int)lo.u | ((unsigned int)hi.u << 16);
                __hip_atomic_store(&hbuf[((par*NBG + bg)*NCB + cb)*128 + (u_bl*2 + u_l)*16 + (u_d>>1)],
                                   uu, __ATOMIC_RELAXED, __HIP_MEMORY_SCOPE_AGENT);
            }
        }
        // stage x(p+1)
        if (tid >= 512 && p + 1 < TT) {
            f16x4 h; h[0]=(_Float16)xv.x; h[1]=(_Float16)xv.y; h[2]=(_Float16)xv.z; h[3]=(_Float16)xv.w;
            *(f16x4*)&rows[xbl*RS + xkq*4] = h;
        }

        if (p == TT) break;

        if (tid < 256) __threadfence();     // publishes visible before flag
        __syncthreads();   // S2

        if (tid == 7)
            __hip_atomic_store(&flg[((par*NBG + bg)*NCB + cb)*16], p + 1,
                               __ATOMIC_RELEASE, __HIP_MEMORY_SCOPE_AGENT);
        __asm__ __volatile__("" ::: "memory");
        if (tid < 7) {
            const int cbp = tid + (tid >= cb);
            const int fidx = ((par*NBG + bg)*NCB + cbp)*16;
            while (__hip_atomic_load(&flg[fidx], __ATOMIC_ACQUIRE, __HIP_MEMORY_SCOPE_AGENT) < p + 1) { }
        }
        __syncthreads();   // S3

        // gather 7 peers' slices -> rows h0/h1
        for (int task = tid; task < 896; task += NTHR) {
            int pi = task >> 7;
            int cbp = pi + (pi >= cb);
            int q = task & 127;                 // (bl*2+l)*16 + dq
            unsigned int uu = __hip_atomic_load(&hbuf[((par*NBG + bg)*NCB + cbp)*128 + q],
                                                __ATOMIC_RELAXED, __HIP_MEMORY_SCOPE_AGENT);
            int dq = q & 15, l = (q >> 4) & 1, bl = q >> 5;
            DU du; du.u = uu;
            *(h2t*)&rows[((l ? 8 : 4) + bl)*RS + cbp*32 + dq*2] = du.h;
        }
        __syncthreads();   // S4
    }
}

extern "C" void kernel_launch(void* const* d_in, const int* in_sizes, int n_in,
                              void* d_out, int out_size, void* d_ws, size_t ws_size,
                              hipStream_t stream) {
    const float* x    = (const float*)d_in[0];
    const float* W_xh = (const float*)d_in[1];
    const float* b_xh = (const float*)d_in[2];
    const float* W_hh = (const float*)d_in[3];
    const float* b_hh = (const float*)d_in[4];
    float* out = (float*)d_out;

    unsigned int* hbuf = (unsigned int*)d_ws;                     // 128 KB
    int* flg = (int*)((char*)d_ws + (256 << 10));                 // 16 KB

    init_ws<<<16, 256, 0, stream>>>(flg);
    lstm_ws<<<NCB*NBG, NTHR, 0, stream>>>(x, W_xh, b_xh, W_hh, b_hh, out, hbuf, flg);
}

// Round 5
// 17156.456 us; speedup vs baseline: 1.6240x; 1.6240x over previous
//
#include <hip/hip_runtime.h>
#include <hip/hip_fp16.h>

#define BB 64
#define TT 2048
#define DD 256
#define HH 256
#define CHUNK 256
#define NCHUNK 8
#define KV 192          // k-range held in VGPRs
#define KL 64           // k-range held in LDS (KV..255)

typedef _Float16 h2t   __attribute__((ext_vector_type(2)));
typedef _Float16 f16x4 __attribute__((ext_vector_type(4)));
typedef _Float16 f16x8 __attribute__((ext_vector_type(8)));
union V8 { f16x8 v; h2t p[4]; };

__device__ __forceinline__ float sigm(float v){ return __builtin_amdgcn_rcpf(1.f+__expf(-v)); }
__device__ __forceinline__ float tanh_f(float v){ float e=__expf(2.f*v); return 1.f-2.f*__builtin_amdgcn_rcpf(e+1.f); }

// Pack W [256][1024] f32 (k-major) into f16 layout [k/8][1024][8] (for the GEMM)
__global__ void pack_w(const float* __restrict__ w, _Float16* __restrict__ o) {
    int idx = blockIdx.x * 256 + threadIdx.x;
    int j = idx & 1023;
    int k = idx >> 10;
    o[(((k >> 3) * 1024) + j) * 8 + (k & 7)] = (_Float16)w[idx];
}

// gx = x @ W_xh + b_xh for t in [t0, t0+256), all 64 batches.  (round-2 proven)
__global__ __launch_bounds__(256) void gx_gemm(
    const float* __restrict__ x,
    const _Float16* __restrict__ Wx,   // packed [32][1024][8]
    const float* __restrict__ b_xh,
    _Float16* __restrict__ gx,
    int t0)
{
    __shared__ _Float16 xl[64 * 280];

    const int tid = threadIdx.x;
    const int nb = blockIdx.x;   // col block 0..15
    const int rb = blockIdx.y;   // row block 0..255

    for (int it = 0; it < 16; ++it) {
        int idx = it * 256 + tid;
        int row = idx >> 6, kq = idx & 63;
        int rlin = rb * 64 + row;
        int b = rlin >> 8, tl = rlin & 255;
        float4 v = *(const float4*)&x[((size_t)b * TT + (t0 + tl)) * DD + kq * 4];
        f16x4 h;
        h[0] = (_Float16)v.x; h[1] = (_Float16)v.y;
        h[2] = (_Float16)v.z; h[3] = (_Float16)v.w;
        *(f16x4*)&xl[row * 280 + kq * 4] = h;
    }
    __syncthreads();

    const int ty = tid >> 4, tx = tid & 15;
    const int col0 = nb * 64 + tx * 4;
    const f16x8* __restrict__ wxp = (const f16x8*)Wx;

    float acc[4][4] = {};
#pragma unroll 2
    for (int kk = 0; kk < 32; ++kk) {
        V8 wv[4], xv[4];
#pragma unroll
        for (int c = 0; c < 4; ++c) wv[c].v = wxp[kk * 1024 + col0 + c];
#pragma unroll
        for (int r = 0; r < 4; ++r)
            xv[r].v = *(const f16x8*)&xl[(ty + 16 * r) * 280 + kk * 8];
#pragma unroll
        for (int r = 0; r < 4; ++r)
#pragma unroll
            for (int c = 0; c < 4; ++c)
#pragma unroll
                for (int q = 0; q < 4; ++q)
                    acc[r][c] = __builtin_amdgcn_fdot2(xv[r].p[q], wv[c].p[q], acc[r][c], false);
    }

    float bb[4];
#pragma unroll
    for (int c = 0; c < 4; ++c) bb[c] = b_xh[col0 + c];

#pragma unroll
    for (int r = 0; r < 4; ++r) {
        int rlin = rb * 64 + ty + 16 * r;
        int b = rlin >> 8, tl = rlin & 255;
        f16x4 o;
#pragma unroll
        for (int c = 0; c < 4; ++c) o[c] = (_Float16)(acc[r][c] + bb[c]);
        *(f16x4*)&gx[((size_t)(b * CHUNK + tl)) * 1024 + col0] = o;
    }
}

// Serial recurrence, weight-resident: 64 blocks (1/batch), 256 threads.
// Thread t owns gate cols {t, 256+t, 512+t, 768+t} (= i,f,g,o of h-dim t).
// W_hh k in [0,KV) in VGPRs (96 f16x8), k in [KV,256) in LDS (128 KB).
__global__ __launch_bounds__(256, 1) void lstm_serial(
    const float* __restrict__ W_hh,    // [256][1024] f32
    const float* __restrict__ b_hh,    // [1024]
    const _Float16* __restrict__ gx,   // [64][CHUNK][1024] (x@Wx + b_xh)
    float* __restrict__ out,
    float* __restrict__ st,            // h0,h1,c0,c1 each [64][256] f32
    int t0, int nph, int first, int last)
{
    __shared__ _Float16 Wl[(KL/8) * 1024 * 8];   // [kk][col][8] = 128 KB
    __shared__ _Float16 h_lds[2][2][256];        // [parity][layer][dim]

    const int tid = threadIdx.x;
    const int b = blockIdx.x;

    float bh[4];
#pragma unroll
    for (int g = 0; g < 4; ++g) bh[g] = b_hh[g * 256 + tid];

    // ---- stage LDS weight slice: k in [KV, 256) ----
#pragma unroll
    for (int g = 0; g < 4; ++g)
#pragma unroll
        for (int kk = 0; kk < KL/8; ++kk) {
            f16x8 w;
#pragma unroll
            for (int e = 0; e < 8; ++e)
                w[e] = (_Float16)W_hh[(size_t)(KV + kk*8 + e) * 1024 + g * 256 + tid];
            *(f16x8*)&Wl[(size_t)(kk * 1024 + g * 256 + tid) * 8] = w;
        }

    // ---- weight registers: k in [0, KV), 4 cols x 24 chunks (static indexing only!) ----
    V8 wv[4 * (KV/8)];
#pragma unroll
    for (int g = 0; g < 4; ++g)
#pragma unroll
        for (int kk = 0; kk < KV/8; ++kk) {
            f16x8 w;
#pragma unroll
            for (int e = 0; e < 8; ++e)
                w[e] = (_Float16)W_hh[(size_t)(kk*8 + e) * 1024 + g * 256 + tid];
            wv[g * (KV/8) + kk].v = w;
        }

    // ---- state ----
    float h0keep = 0.f, h1keep = 0.f, c0 = 0.f, c1 = 0.f;
    if (!first) {
        h0keep = st[0 * 16384 + b * 256 + tid];
        h1keep = st[1 * 16384 + b * 256 + tid];
        c0     = st[2 * 16384 + b * 256 + tid];
        c1     = st[3 * 16384 + b * 256 + tid];
    }
    h_lds[0][0][tid] = (_Float16)h0keep;
    h_lds[0][1][tid] = (_Float16)h1keep;
    __syncthreads();

    for (int p = 0; p < nph; ++p) {
        const int par = p & 1;
        const bool l0act = (p < CHUNK);
        const bool l1act = !(first && p == 0);

        // gx for this thread's 4 gate cols (issued early, consumed ~2000 cy later)
        float gx0 = 0.f, gx1 = 0.f, gx2 = 0.f, gx3 = 0.f;
        if (l0act) {
            const _Float16* gp = &gx[((size_t)b * CHUNK + p) * 1024 + tid];
            gx0 = (float)gp[0]; gx1 = (float)gp[256];
            gx2 = (float)gp[512]; gx3 = (float)gp[768];
        }

        const _Float16* hb0 = &h_lds[par][0][0];
        const _Float16* hb1 = &h_lds[par][1][0];

        float d0[4] = {0.f,0.f,0.f,0.f};
        float d1[4] = {0.f,0.f,0.f,0.f};

        // VGPR-weight section: k in [0, KV)
#pragma unroll
        for (int kk = 0; kk < KV/8; ++kk) {
            V8 h0c, h1c;
            h0c.v = *(const f16x8*)&hb0[kk * 8];
            h1c.v = *(const f16x8*)&hb1[kk * 8];
#pragma unroll
            for (int g = 0; g < 4; ++g) {
#pragma unroll
                for (int q = 0; q < 4; ++q) {
                    d0[g] = __builtin_amdgcn_fdot2(h0c.p[q], wv[g*(KV/8)+kk].p[q], d0[g], false);
                    d1[g] = __builtin_amdgcn_fdot2(h1c.p[q], wv[g*(KV/8)+kk].p[q], d1[g], false);
                }
            }
        }
        // LDS-weight section: k in [KV, 256)
#pragma unroll
        for (int kk = 0; kk < KL/8; ++kk) {
            V8 h0c, h1c;
            h0c.v = *(const f16x8*)&hb0[KV + kk * 8];
            h1c.v = *(const f16x8*)&hb1[KV + kk * 8];
#pragma unroll
            for (int g = 0; g < 4; ++g) {
                V8 w;
                w.v = *(const f16x8*)&Wl[(size_t)(kk * 1024 + g * 256 + tid) * 8];
#pragma unroll
                for (int q = 0; q < 4; ++q) {
                    d0[g] = __builtin_amdgcn_fdot2(h0c.p[q], w.p[q], d0[g], false);
                    d1[g] = __builtin_amdgcn_fdot2(h1c.p[q], w.p[q], d1[g], false);
                }
            }
        }

        // layer 0, step t0+p
        float h0n = h0keep, h1n = h1keep;
        if (l0act) {
            float gi = gx0 + d0[0] + bh[0];
            float gf = gx1 + d0[1] + bh[1];
            float gg = gx2 + d0[2] + bh[2];
            float go = gx3 + d0[3] + bh[3];
            c0 = c0 * sigm(gf) + sigm(gi) * tanh_f(gg);
            h0n = sigm(go) * tanh_f(c0);
            h0keep = h0n;
        }
        // layer 1, step t0+p-1 (input = h0(t0+p-1) -> same d0; hidden = h1(t0+p-2) -> d1)
        if (l1act) {
            float gi = d0[0] + d1[0] + 2.f * bh[0];
            float gf = d0[1] + d1[1] + 2.f * bh[1];
            float gg = d0[2] + d1[2] + 2.f * bh[2];
            float go = d0[3] + d1[3] + 2.f * bh[3];
            c1 = c1 * sigm(gf) + sigm(gi) * tanh_f(gg);
            h1n = sigm(go) * tanh_f(c1);
            h1keep = h1n;
            out[((size_t)b * TT + (t0 + p - 1)) * HH + tid] = h1n;
        }

        h_lds[par ^ 1][0][tid] = (_Float16)h0n;
        h_lds[par ^ 1][1][tid] = (_Float16)h1n;
        __syncthreads();
    }

    st[0 * 16384 + b * 256 + tid] = h0keep;
    st[1 * 16384 + b * 256 + tid] = h1keep;
    st[2 * 16384 + b * 256 + tid] = c0;
    st[3 * 16384 + b * 256 + tid] = c1;
    if (last) {
        const size_t FIN = (size_t)BB * TT * HH;
        out[FIN +                 b * 256 + tid] = h0keep;   // h_fin[0]
        out[FIN + 16384 +         b * 256 + tid] = h1keep;   // h_fin[1]
        out[FIN + 32768 +         b * 256 + tid] = c0;       // c_fin[0]
        out[FIN + 32768 + 16384 + b * 256 + tid] = c1;       // c_fin[1]
    }
}

extern "C" void kernel_launch(void* const* d_in, const int* in_sizes, int n_in,
                              void* d_out, int out_size, void* d_ws, size_t ws_size,
                              hipStream_t stream) {
    const float* x    = (const float*)d_in[0];
    const float* W_xh = (const float*)d_in[1];
    const float* b_xh = (const float*)d_in[2];
    const float* W_hh = (const float*)d_in[3];
    const float* b_hh = (const float*)d_in[4];
    float* out = (float*)d_out;

    char* ws = (char*)d_ws;
    _Float16* wxp = (_Float16*)(ws);                    // 512 KB packed W_xh
    float*    st  = (float*)(ws + (512 << 10));         // 256 KB carried state
    _Float16* gx  = (_Float16*)(ws + (768 << 10));      // 32 MB gx chunk

    pack_w<<<1024, 256, 0, stream>>>(W_xh, wxp);

    for (int c = 0; c < NCHUNK; ++c) {
        int t0 = c * CHUNK;
        gx_gemm<<<dim3(16, 256), 256, 0, stream>>>(x, wxp, b_xh, gx, t0);
        lstm_serial<<<BB, 256, 0, stream>>>(W_hh, b_hh, gx, out, st,
                                            t0, (c == NCHUNK - 1) ? CHUNK + 1 : CHUNK,
                                            c == 0, c == NCHUNK - 1);
    }
}